// Round 1
// baseline (352.495 us; speedup 1.0000x reference)
//
#include <hip/hip_runtime.h>

// EncoderBlock: pre-LN MHSA + pre-LN GELU FFN.  S=2048 D=1024 H=16 DK=64 MLP=4096.
// All GEMMs: bf16 MFMA 16x16x32, m97-style bt-GEMM (A[M,K] x Bt[N,K]).
// Attention: flash (online softmax), no S x S materialization.

constexpr int kS = 2048, kD = 1024, kH = 16, kDK = 64, kMLP = 4096;
constexpr float kEps = 1e-5f;

using u16 = unsigned short;
using u32 = unsigned int;
typedef float f32x4 __attribute__((ext_vector_type(4)));
typedef short bf16x8 __attribute__((ext_vector_type(8)));   // 8 bf16 = 4 VGPRs

__device__ __forceinline__ u16 f2b(float f) {               // fp32 -> bf16 (RNE)
  u32 u = __builtin_bit_cast(u32, f);
  return (u16)((u + 0x7fffu + ((u >> 16) & 1u)) >> 16);
}

typedef const __attribute__((address_space(1))) u32* gas1;
typedef __attribute__((address_space(3))) u32* las3;
__device__ __forceinline__ void async16(const void* g, void* l) {
  // global -> LDS DMA, 16B/lane; LDS dest = wave-uniform base + lane*16
  __builtin_amdgcn_global_load_lds((gas1)g, (las3)l, 16, 0, 0);
}

// ---------------- LayerNorm: fp32 [row][1024] -> bf16 ----------------
__global__ __launch_bounds__(256)
void ln_kernel(const float* __restrict__ x, const float* __restrict__ g,
               const float* __restrict__ b, u16* __restrict__ out) {
  __shared__ float red[8];
  const int row = blockIdx.x, tid = threadIdx.x;
  const float4 v = *(const float4*)(x + (size_t)row * kD + tid * 4);
  float s = v.x + v.y + v.z + v.w;
  float ss = v.x * v.x + v.y * v.y + v.z * v.z + v.w * v.w;
#pragma unroll
  for (int d = 1; d < 64; d <<= 1) { s += __shfl_xor(s, d); ss += __shfl_xor(ss, d); }
  if ((tid & 63) == 0) { red[tid >> 6] = s; red[4 + (tid >> 6)] = ss; }
  __syncthreads();
  const float m = (red[0] + red[1] + red[2] + red[3]) * (1.f / kD);
  const float var = (red[4] + red[5] + red[6] + red[7]) * (1.f / kD) - m * m;
  const float r = rsqrtf(var + kEps);
  const float4 gv = *(const float4*)(g + tid * 4);
  const float4 bv = *(const float4*)(b + tid * 4);
  ushort4 o;
  o.x = f2b((v.x - m) * r * gv.x + bv.x);
  o.y = f2b((v.y - m) * r * gv.y + bv.y);
  o.z = f2b((v.z - m) * r * gv.z + bv.z);
  o.w = f2b((v.w - m) * r * gv.w + bv.w);
  *(ushort4*)(out + (size_t)row * kD + tid * 4) = o;
}

// ------------- transpose + fp32->bf16:  out[c][r] = in[r][c] -------------
__global__ __launch_bounds__(256)
void transpose_cvt(const float* __restrict__ in, u16* __restrict__ out, int R, int C) {
  __shared__ float tile[32][33];
  const int c0 = blockIdx.x * 32, r0 = blockIdx.y * 32;
  const int x = threadIdx.x, y = threadIdx.y;
#pragma unroll
  for (int i = 0; i < 4; ++i)
    tile[y + i * 8][x] = in[(size_t)(r0 + y + i * 8) * C + c0 + x];
  __syncthreads();
#pragma unroll
  for (int i = 0; i < 4; ++i)
    out[(size_t)(c0 + y + i * 8) * R + r0 + x] = f2b(tile[x][y + i * 8]);
}

__global__ void concat_bias(const float* __restrict__ bq, const float* __restrict__ bk,
                            const float* __restrict__ bv, float* __restrict__ out) {
  int i = blockIdx.x * 256 + threadIdx.x;  // 3072
  out[i] = i < kD ? bq[i] : (i < 2 * kD ? bk[i - kD] : bv[i - 2 * kD]);
}

// --- per-head V transpose: qkv[s][2048+h*64+d] (bf16) -> vt[h][d][s] (bf16) ---
__global__ __launch_bounds__(256)
void vtrans(const u16* __restrict__ qkv, u16* __restrict__ vt) {
  __shared__ u16 t[64][72];
  const int s0 = blockIdx.x * 64, h = blockIdx.y, tid = threadIdx.x;
#pragma unroll
  for (int r = 0; r < 2; ++r) {
    int chunk = r * 256 + tid, row = chunk >> 3, col = (chunk & 7) * 8;
    uint4 v = *(const uint4*)(qkv + (size_t)(s0 + row) * 3072 + 2 * kD + h * 64 + col);
    *(uint4*)(&t[row][col]) = v;
  }
  __syncthreads();
#pragma unroll
  for (int r = 0; r < 2; ++r) {
    int chunk = r * 256 + tid, drow = chunk >> 3, scol = (chunk & 7) * 8;
    u16 tmp[8];
#pragma unroll
    for (int j = 0; j < 8; ++j) tmp[j] = t[scol + j][drow];
    *(uint4*)(vt + (size_t)h * 64 * kS + (size_t)drow * kS + s0 + scol) = *(uint4*)tmp;
  }
}

// ---------------- bt-GEMM: C[M,N] = A[M,K](bf16) x Bt[N,K](bf16) + bias ----------------
// EPI 0: bf16 out   EPI 1: bf16 gelu(erf) out   EPI 2: fp32 out + residual
template <int BN, int WM, int WN, int EPI>
__global__ __launch_bounds__(256, 2)
void gemm_bt(const u16* __restrict__ A, const u16* __restrict__ Bt,
             const float* __restrict__ bias, const float* __restrict__ res,
             void* __restrict__ Cout, int N, int K) {
  constexpr int BM = 128, BK = 32;
  constexpr int MT = BM / (WM * 16);
  constexpr int NT = BN / (WN * 16);
  constexpr int RA = BM * BK / 2048;
  constexpr int RB = BN * BK / 2048;
  __shared__ u16 As[BM * BK];
  __shared__ u16 Bs[BN * BK];
  const int tid = threadIdx.x;
  const int w = tid >> 6, l = tid & 63;
  const int wm = w / WN, wn = w % WN;
  const int row0 = blockIdx.y * BM, col0 = blockIdx.x * BN;

  const u16* Ag = A + (size_t)(row0 + w * 16 + (l >> 2)) * K + (l & 3) * 8;
  const u16* Bg = Bt + (size_t)(col0 + w * 16 + (l >> 2)) * K + (l & 3) * 8;
  u16* AsW = As + w * 512;
  u16* BsW = Bs + w * 512;

  f32x4 acc[MT][NT] = {};

  for (int kt = 0; kt < K; kt += BK) {
#pragma unroll
    for (int r = 0; r < RA; ++r) async16(Ag + (size_t)r * 64 * K + kt, AsW + r * 2048);
#pragma unroll
    for (int r = 0; r < RB; ++r) async16(Bg + (size_t)r * 64 * K + kt, BsW + r * 2048);
    __syncthreads();  // compiler drains vmcnt before s_barrier -> LDS valid
    bf16x8 af[MT], bfr[NT];
#pragma unroll
    for (int i = 0; i < MT; ++i)
      af[i] = *(const bf16x8*)(As + (wm * (BM / WM) + i * 16 + (l & 15)) * BK + (l >> 4) * 8);
#pragma unroll
    for (int j = 0; j < NT; ++j)
      bfr[j] = *(const bf16x8*)(Bs + (wn * (BN / WN) + j * 16 + (l & 15)) * BK + (l >> 4) * 8);
#pragma unroll
    for (int i = 0; i < MT; ++i)
#pragma unroll
      for (int j = 0; j < NT; ++j)
        acc[i][j] = __builtin_amdgcn_mfma_f32_16x16x32_bf16(af[i], bfr[j], acc[i][j], 0, 0, 0);
    __syncthreads();
  }

#pragma unroll
  for (int i = 0; i < MT; ++i) {
    const int row = row0 + wm * (BM / WM) + i * 16 + ((l >> 4) << 2);
#pragma unroll
    for (int j = 0; j < NT; ++j) {
      const int col = col0 + wn * (BN / WN) + j * 16 + (l & 15);
      const float bb = bias[col];
#pragma unroll
      for (int r = 0; r < 4; ++r) {
        const size_t idx = (size_t)(row + r) * N + col;
        float v = acc[i][j][r] + bb;
        if constexpr (EPI == 0) {
          ((u16*)Cout)[idx] = f2b(v);
        } else if constexpr (EPI == 1) {
          ((u16*)Cout)[idx] = f2b(0.5f * v * (1.f + erff(v * 0.7071067811865475f)));
        } else {
          ((float*)Cout)[idx] = v + res[idx];
        }
      }
    }
  }
}

// ---------------- flash attention ----------------
// grid (S/64, H), 256 thr (4 waves); wave w owns q-rows [q0+w*16, +16).
// Per iter: K-tile 128 keys.  og written in natural [H][S][DK] order, which
// reinterprets exactly as the reference's o.reshape(S, D) row-major A matrix.
__global__ __launch_bounds__(256, 2)
void flash_attn(const u16* __restrict__ qkv, const u16* __restrict__ vt,
                u16* __restrict__ og) {
  constexpr int LQ = 72;    // 64 + 8 pad (breaks b128 bank conflicts)
  constexpr int LV = 136;   // 128 + 8 pad
  __shared__ u16 Qs[64 * LQ];
  __shared__ u16 Ks[128 * LQ];
  __shared__ u16 Vs[64 * LV];       // V^T tile: [d][s]
  __shared__ u16 Ps[4][16 * LV];    // per-wave P (C-layout -> A-layout round trip)
  const int tid = threadIdx.x, w = tid >> 6, l = tid & 63;
  const int h = blockIdx.y, q0 = blockIdx.x * 64;

  // stage Q [64][64]
#pragma unroll
  for (int r = 0; r < 2; ++r) {
    int chunk = r * 256 + tid, row = chunk >> 3, col = (chunk & 7) * 8;
    uint4 v = *(const uint4*)(qkv + (size_t)(q0 + row) * 3072 + h * 64 + col);
    *(uint4*)(&Qs[row * LQ + col]) = v;
  }
  __syncthreads();
  bf16x8 qa[2];
#pragma unroll
  for (int kq = 0; kq < 2; ++kq)
    qa[kq] = *(const bf16x8*)(&Qs[(w * 16 + (l & 15)) * LQ + kq * 32 + (l >> 4) * 8]);

  f32x4 oacc[4] = {};
  float mi[4], li[4];
#pragma unroll
  for (int r = 0; r < 4; ++r) { mi[r] = -1e30f; li[r] = 0.f; }

  for (int kt = 0; kt < kS; kt += 128) {
    __syncthreads();  // prev iter done reading Ks/Vs
    // stage K-tile [128][64]
#pragma unroll
    for (int r = 0; r < 4; ++r) {
      int chunk = r * 256 + tid, row = chunk >> 3, col = (chunk & 7) * 8;
      uint4 v = *(const uint4*)(qkv + (size_t)(kt + row) * 3072 + kD + h * 64 + col);
      *(uint4*)(&Ks[row * LQ + col]) = v;
    }
    // stage V^T tile [64][128]
#pragma unroll
    for (int r = 0; r < 4; ++r) {
      int chunk = r * 256 + tid, row = chunk >> 4, col = (chunk & 15) * 8;
      uint4 v = *(const uint4*)(vt + (size_t)h * 64 * kS + (size_t)row * kS + kt + col);
      *(uint4*)(&Vs[row * LV + col]) = v;
    }
    __syncthreads();

    // S = Q K^T  (16 q-rows x 128 cols per wave)
    f32x4 s[8];
#pragma unroll
    for (int n = 0; n < 8; ++n) {
      f32x4 z = {};
      bf16x8 kb0 = *(const bf16x8*)(&Ks[(n * 16 + (l & 15)) * LQ + (l >> 4) * 8]);
      bf16x8 kb1 = *(const bf16x8*)(&Ks[(n * 16 + (l & 15)) * LQ + 32 + (l >> 4) * 8]);
      z = __builtin_amdgcn_mfma_f32_16x16x32_bf16(qa[0], kb0, z, 0, 0, 0);
      z = __builtin_amdgcn_mfma_f32_16x16x32_bf16(qa[1], kb1, z, 0, 0, 0);
      s[n] = z;
    }
    // online softmax (rows live on 16 lanes sharing l>>4; cols = l&15 across 8 frags)
    float alpha[4];
#pragma unroll
    for (int r = 0; r < 4; ++r) {
      float m = -1e30f;
#pragma unroll
      for (int n = 0; n < 8; ++n) m = fmaxf(m, s[n][r]);
#pragma unroll
      for (int d = 1; d < 16; d <<= 1) m = fmaxf(m, __shfl_xor(m, d));
      m *= 0.125f;  // 1/sqrt(DK); positive scale commutes with max
      float mn = fmaxf(mi[r], m);
      alpha[r] = __expf(mi[r] - mn);
      mi[r] = mn;
      li[r] *= alpha[r];
    }
#pragma unroll
    for (int n = 0; n < 4; ++n)
#pragma unroll
      for (int r = 0; r < 4; ++r) oacc[n][r] *= alpha[r];
    float rs[4] = {0.f, 0.f, 0.f, 0.f};
#pragma unroll
    for (int n = 0; n < 8; ++n)
#pragma unroll
      for (int r = 0; r < 4; ++r) {
        float pv = __expf(s[n][r] * 0.125f - mi[r]);
        rs[r] += pv;
        Ps[w][((l >> 4) * 4 + r) * LV + n * 16 + (l & 15)] = f2b(pv);
      }
#pragma unroll
    for (int r = 0; r < 4; ++r) {
      float t = rs[r];
#pragma unroll
      for (int d = 1; d < 16; d <<= 1) t += __shfl_xor(t, d);
      li[r] += t;
    }
    // O += P V   (P 16x128 from own-wave LDS region; V^T in Vs)
    bf16x8 pa[4];
#pragma unroll
    for (int ks = 0; ks < 4; ++ks)
      pa[ks] = *(const bf16x8*)(&Ps[w][(l & 15) * LV + ks * 32 + (l >> 4) * 8]);
#pragma unroll
    for (int n = 0; n < 4; ++n)
#pragma unroll
      for (int ks = 0; ks < 4; ++ks) {
        bf16x8 vb = *(const bf16x8*)(&Vs[(n * 16 + (l & 15)) * LV + ks * 32 + (l >> 4) * 8]);
        oacc[n] = __builtin_amdgcn_mfma_f32_16x16x32_bf16(pa[ks], vb, oacc[n], 0, 0, 0);
      }
  }
  // epilogue: normalize, write og[h][s][d] (contiguous == reference reshape)
#pragma unroll
  for (int r = 0; r < 4; ++r) {
    float inv = 1.f / li[r];
    int srow = q0 + w * 16 + (l >> 4) * 4 + r;
#pragma unroll
    for (int n = 0; n < 4; ++n) {
      int d = n * 16 + (l & 15);
      og[(size_t)h * kS * kDK + (size_t)srow * kDK + d] = f2b(oacc[n][r] * inv);
    }
  }
}

extern "C" void kernel_launch(void* const* d_in, const int* in_sizes, int n_in,
                              void* d_out, int out_size, void* d_ws, size_t ws_size,
                              hipStream_t stream) {
  const float* x = (const float*)d_in[0];
  const float* wq = (const float*)d_in[1];
  const float* bq = (const float*)d_in[2];
  const float* wk = (const float*)d_in[3];
  const float* bk = (const float*)d_in[4];
  const float* wv = (const float*)d_in[5];
  const float* bv = (const float*)d_in[6];
  const float* wo = (const float*)d_in[7];
  const float* bo = (const float*)d_in[8];
  const float* w1 = (const float*)d_in[9];
  const float* b1 = (const float*)d_in[10];
  const float* w2 = (const float*)d_in[11];
  const float* b2 = (const float*)d_in[12];
  const float* ln1g = (const float*)d_in[13];
  const float* ln1b = (const float*)d_in[14];
  const float* ln2g = (const float*)d_in[15];
  const float* ln2b = (const float*)d_in[16];
  float* out = (float*)d_out;

  char* p = (char*)d_ws;
  auto alloc = [&](size_t bytes) { void* q = (void*)p; p += (bytes + 255) & ~(size_t)255; return q; };
  u16* h1 = (u16*)alloc((size_t)kS * kD * 2);
  u16* wqkvt = (u16*)alloc((size_t)3 * kD * kD * 2);
  float* bqkv = (float*)alloc((size_t)3 * kD * 4);
  u16* qkv = (u16*)alloc((size_t)kS * 3 * kD * 2);
  u16* vt = (u16*)alloc((size_t)kH * kDK * kS * 2);
  u16* og = (u16*)alloc((size_t)kS * kD * 2);
  u16* wot = (u16*)alloc((size_t)kD * kD * 2);
  float* x2 = (float*)alloc((size_t)kS * kD * 4);
  u16* h2 = (u16*)alloc((size_t)kS * kD * 2);
  u16* w1t = (u16*)alloc((size_t)kD * kMLP * 2);
  u16* fbuf = (u16*)alloc((size_t)kS * kMLP * 2);
  u16* w2t = (u16*)alloc((size_t)kMLP * kD * 2);

  dim3 tb(32, 8);
  transpose_cvt<<<dim3(kD / 32, kD / 32), tb, 0, stream>>>(wq, wqkvt, kD, kD);
  transpose_cvt<<<dim3(kD / 32, kD / 32), tb, 0, stream>>>(wk, wqkvt + kD * kD, kD, kD);
  transpose_cvt<<<dim3(kD / 32, kD / 32), tb, 0, stream>>>(wv, wqkvt + 2 * kD * kD, kD, kD);
  transpose_cvt<<<dim3(kD / 32, kD / 32), tb, 0, stream>>>(wo, wot, kD, kD);
  transpose_cvt<<<dim3(kMLP / 32, kD / 32), tb, 0, stream>>>(w1, w1t, kD, kMLP);
  transpose_cvt<<<dim3(kD / 32, kMLP / 32), tb, 0, stream>>>(w2, w2t, kMLP, kD);
  concat_bias<<<dim3(12), dim3(256), 0, stream>>>(bq, bk, bv, bqkv);

  ln_kernel<<<dim3(kS), dim3(256), 0, stream>>>(x, ln1g, ln1b, h1);
  // fused QKV: [2048,1024] x [3072,1024]^T -> qkv bf16 [2048,3072]
  gemm_bt<128, 2, 2, 0><<<dim3(3 * kD / 128, kS / 128), dim3(256), 0, stream>>>(
      h1, wqkvt, bqkv, nullptr, qkv, 3 * kD, kD);
  vtrans<<<dim3(kS / 64, kH), dim3(256), 0, stream>>>(qkv, vt);
  flash_attn<<<dim3(kS / 64, kH), dim3(256), 0, stream>>>(qkv, vt, og);
  // O-proj + residual (fp32): x2 = x + og @ wo + bo
  gemm_bt<64, 4, 1, 2><<<dim3(kD / 64, kS / 128), dim3(256), 0, stream>>>(
      og, wot, bo, x, x2, kD, kD);
  ln_kernel<<<dim3(kS), dim3(256), 0, stream>>>(x2, ln2g, ln2b, h2);
  // FFN1 + exact GELU -> bf16 [2048,4096]
  gemm_bt<128, 2, 2, 1><<<dim3(kMLP / 128, kS / 128), dim3(256), 0, stream>>>(
      h2, w1t, b1, nullptr, fbuf, kMLP, kD);
  // FFN2 + residual -> d_out fp32
  gemm_bt<64, 4, 1, 2><<<dim3(kD / 64, kS / 128), dim3(256), 0, stream>>>(
      fbuf, w2t, b2, x2, out, kD, kMLP);
}

// Round 2
// 321.460 us; speedup vs baseline: 1.0965x; 1.0965x over previous
//
#include <hip/hip_runtime.h>

// EncoderBlock: pre-LN MHSA + pre-LN GELU FFN.  S=2048 D=1024 H=16 DK=64 MLP=4096.
// All GEMMs: bf16 MFMA 16x16x32, m97-style bt-GEMM (A[M,K] x Bt[N,K]), 128x128 tile,
// XOR-swizzled LDS (kills the 8-way b128 bank conflicts of stride-64B rows).
// N=1024 GEMMs (O-proj, FFN2) use split-K + fused reduce(+bias+residual).
// Attention: flash (online softmax), no S x S materialization.

constexpr int kS = 2048, kD = 1024, kH = 16, kDK = 64, kMLP = 4096;
constexpr float kEps = 1e-5f;

using u16 = unsigned short;
using u32 = unsigned int;
typedef float f32x4 __attribute__((ext_vector_type(4)));
typedef short bf16x8 __attribute__((ext_vector_type(8)));   // 8 bf16 = 4 VGPRs

__device__ __forceinline__ u16 f2b(float f) {               // fp32 -> bf16 (RNE)
  u32 u = __builtin_bit_cast(u32, f);
  return (u16)((u + 0x7fffu + ((u >> 16) & 1u)) >> 16);
}

typedef const __attribute__((address_space(1))) u32* gas1;
typedef __attribute__((address_space(3))) u32* las3;
__device__ __forceinline__ void async16(const void* g, void* l) {
  // global -> LDS DMA, 16B/lane; LDS dest = wave-uniform base + lane*16
  __builtin_amdgcn_global_load_lds((gas1)g, (las3)l, 16, 0, 0);
}

// ---------------- LayerNorm: fp32 [row][1024] -> bf16 ----------------
__global__ __launch_bounds__(256)
void ln_kernel(const float* __restrict__ x, const float* __restrict__ g,
               const float* __restrict__ b, u16* __restrict__ out) {
  __shared__ float red[8];
  const int row = blockIdx.x, tid = threadIdx.x;
  const float4 v = *(const float4*)(x + (size_t)row * kD + tid * 4);
  float s = v.x + v.y + v.z + v.w;
  float ss = v.x * v.x + v.y * v.y + v.z * v.z + v.w * v.w;
#pragma unroll
  for (int d = 1; d < 64; d <<= 1) { s += __shfl_xor(s, d); ss += __shfl_xor(ss, d); }
  if ((tid & 63) == 0) { red[tid >> 6] = s; red[4 + (tid >> 6)] = ss; }
  __syncthreads();
  const float m = (red[0] + red[1] + red[2] + red[3]) * (1.f / kD);
  const float var = (red[4] + red[5] + red[6] + red[7]) * (1.f / kD) - m * m;
  const float r = rsqrtf(var + kEps);
  const float4 gv = *(const float4*)(g + tid * 4);
  const float4 bv = *(const float4*)(b + tid * 4);
  ushort4 o;
  o.x = f2b((v.x - m) * r * gv.x + bv.x);
  o.y = f2b((v.y - m) * r * gv.y + bv.y);
  o.z = f2b((v.z - m) * r * gv.z + bv.z);
  o.w = f2b((v.w - m) * r * gv.w + bv.w);
  *(ushort4*)(out + (size_t)row * kD + tid * 4) = o;
}

// ------------- transpose + fp32->bf16:  out[c][r] = in[r][c] -------------
__global__ __launch_bounds__(256)
void transpose_cvt(const float* __restrict__ in, u16* __restrict__ out, int R, int C) {
  __shared__ float tile[32][33];
  const int c0 = blockIdx.x * 32, r0 = blockIdx.y * 32;
  const int x = threadIdx.x, y = threadIdx.y;
#pragma unroll
  for (int i = 0; i < 4; ++i)
    tile[y + i * 8][x] = in[(size_t)(r0 + y + i * 8) * C + c0 + x];
  __syncthreads();
#pragma unroll
  for (int i = 0; i < 4; ++i)
    out[(size_t)(c0 + y + i * 8) * R + r0 + x] = f2b(tile[x][y + i * 8]);
}

__global__ void concat_bias(const float* __restrict__ bq, const float* __restrict__ bk,
                            const float* __restrict__ bv, float* __restrict__ out) {
  int i = blockIdx.x * 256 + threadIdx.x;  // 3072
  out[i] = i < kD ? bq[i] : (i < 2 * kD ? bk[i - kD] : bv[i - 2 * kD]);
}

// --- per-head V transpose: qkv[s][2048+h*64+d] (bf16) -> vt[h][d][s] (bf16) ---
__global__ __launch_bounds__(256)
void vtrans(const u16* __restrict__ qkv, u16* __restrict__ vt) {
  __shared__ u16 t[64][72];
  const int s0 = blockIdx.x * 64, h = blockIdx.y, tid = threadIdx.x;
#pragma unroll
  for (int r = 0; r < 2; ++r) {
    int chunk = r * 256 + tid, row = chunk >> 3, col = (chunk & 7) * 8;
    uint4 v = *(const uint4*)(qkv + (size_t)(s0 + row) * 3072 + 2 * kD + h * 64 + col);
    *(uint4*)(&t[row][col]) = v;
  }
  __syncthreads();
#pragma unroll
  for (int r = 0; r < 2; ++r) {
    int chunk = r * 256 + tid, drow = chunk >> 3, scol = (chunk & 7) * 8;
    u16 tmp[8];
#pragma unroll
    for (int j = 0; j < 8; ++j) tmp[j] = t[scol + j][drow];
    *(uint4*)(vt + (size_t)h * 64 * kS + (size_t)drow * kS + s0 + scol) = *(uint4*)tmp;
  }
}

// ---------------- bt-GEMM: C[M,N] = A[M,K](bf16) x Bt[N,K](bf16) ----------------
// 128x128 tile, BK=32, 4 waves, 16 MFMA/K-iter, XOR-swizzled LDS (2-way banks = free).
// EPI 0: bf16 out (+bias)   EPI 1: bf16 gelu_erf out (+bias)
// EPI 3: fp32 partial store (split-K via blockIdx.z; no bias)
template <int EPI>
__global__ __launch_bounds__(256, 2)
void gemm_bt(const u16* __restrict__ A, const u16* __restrict__ Bt,
             const float* __restrict__ bias, void* __restrict__ Cout,
             int N, int K, int Ksub) {
  constexpr int BM = 128, BN = 128, BK = 32;
  constexpr int MT = 4, NT = 4;              // 16x16 tiles per wave
  __shared__ u16 As[BM * BK];
  __shared__ u16 Bs[BN * BK];
  const int tid = threadIdx.x;
  const int w = tid >> 6, l = tid & 63;
  const int wm = w >> 1, wn = w & 1;
  const int row0 = blockIdx.y * BM, col0 = blockIdx.x * BN;
  const int koff = blockIdx.z * Ksub;

  // staging: lane l stages (row = w*16 + l/4, chunk = l&3), but the LDS slot's
  // chunk is XOR-swizzled, so the global source chunk is (l&3) ^ ((l>>3)&3).
  const int sc = ((l & 3) ^ ((l >> 3) & 3)) * 8;
  const u16* Ag = A + (size_t)(row0 + w * 16 + (l >> 2)) * K + koff + sc;
  const u16* Bg = Bt + (size_t)(col0 + w * 16 + (l >> 2)) * K + koff + sc;
  u16* AsW = As + w * 512;
  u16* BsW = Bs + w * 512;

  f32x4 acc[MT][NT] = {};
  const int q = l >> 4;                      // k-chunk this lane reads for MFMA

  for (int kt = 0; kt < Ksub; kt += BK) {
#pragma unroll
    for (int r = 0; r < 2; ++r) async16(Ag + (size_t)r * 64 * K + kt, AsW + r * 2048);
#pragma unroll
    for (int r = 0; r < 2; ++r) async16(Bg + (size_t)r * 64 * K + kt, BsW + r * 2048);
    __syncthreads();  // compiler drains vmcnt before s_barrier -> LDS valid
    bf16x8 af[MT], bfr[NT];
#pragma unroll
    for (int i = 0; i < MT; ++i) {
      const int ra = wm * 64 + i * 16 + (l & 15);
      af[i] = *(const bf16x8*)(As + ra * 32 + (q ^ ((ra >> 1) & 3)) * 8);
    }
#pragma unroll
    for (int j = 0; j < NT; ++j) {
      const int rb = wn * 64 + j * 16 + (l & 15);
      bfr[j] = *(const bf16x8*)(Bs + rb * 32 + (q ^ ((rb >> 1) & 3)) * 8);
    }
#pragma unroll
    for (int i = 0; i < MT; ++i)
#pragma unroll
      for (int j = 0; j < NT; ++j)
        acc[i][j] = __builtin_amdgcn_mfma_f32_16x16x32_bf16(af[i], bfr[j], acc[i][j], 0, 0, 0);
    __syncthreads();
  }

  float* Pf = nullptr;
  if constexpr (EPI == 3)
    Pf = (float*)Cout + (size_t)blockIdx.z * gridDim.y * BM * N;
#pragma unroll
  for (int i = 0; i < MT; ++i) {
    const int row = row0 + wm * 64 + i * 16 + ((l >> 4) << 2);
#pragma unroll
    for (int j = 0; j < NT; ++j) {
      const int col = col0 + wn * 64 + j * 16 + (l & 15);
      float bb = 0.f;
      if constexpr (EPI != 3) bb = bias[col];
#pragma unroll
      for (int r = 0; r < 4; ++r) {
        const size_t idx = (size_t)(row + r) * N + col;
        float v = acc[i][j][r] + bb;
        if constexpr (EPI == 0) {
          ((u16*)Cout)[idx] = f2b(v);
        } else if constexpr (EPI == 1) {
          ((u16*)Cout)[idx] = f2b(0.5f * v * (1.f + erff(v * 0.7071067811865475f)));
        } else {
          Pf[idx] = v;
        }
      }
    }
  }
}

// ---- split-K reduce: out = sum_s parts[s] + bias + res  (fp32, float4) ----
template <int KS>
__global__ __launch_bounds__(256)
void reduce_add(const float* __restrict__ parts, const float* __restrict__ bias,
                const float* __restrict__ res, float* __restrict__ out,
                int N, size_t strideMN) {
  const size_t b = ((size_t)blockIdx.x * 256 + threadIdx.x) * 4;
  float4 a = *(const float4*)(res + b);
  const float4 bv = *(const float4*)(bias + (b & (size_t)(N - 1)));
  a.x += bv.x; a.y += bv.y; a.z += bv.z; a.w += bv.w;
#pragma unroll
  for (int s = 0; s < KS; ++s) {
    const float4 p = *(const float4*)(parts + s * strideMN + b);
    a.x += p.x; a.y += p.y; a.z += p.z; a.w += p.w;
  }
  *(float4*)(out + b) = a;
}

// ---------------- flash attention ----------------
// grid (S/64, H), 256 thr (4 waves); wave w owns q-rows [q0+w*16, +16).
__global__ __launch_bounds__(256, 2)
void flash_attn(const u16* __restrict__ qkv, const u16* __restrict__ vt,
                u16* __restrict__ og) {
  constexpr int LQ = 72;    // 64 + 8 pad (breaks b128 bank conflicts)
  constexpr int LV = 136;   // 128 + 8 pad
  __shared__ u16 Qs[64 * LQ];
  __shared__ u16 Ks[128 * LQ];
  __shared__ u16 Vs[64 * LV];       // V^T tile: [d][s]
  __shared__ u16 Ps[4][16 * LV];    // per-wave P (C-layout -> A-layout round trip)
  const int tid = threadIdx.x, w = tid >> 6, l = tid & 63;
  const int h = blockIdx.y, q0 = blockIdx.x * 64;

  // stage Q [64][64]
#pragma unroll
  for (int r = 0; r < 2; ++r) {
    int chunk = r * 256 + tid, row = chunk >> 3, col = (chunk & 7) * 8;
    uint4 v = *(const uint4*)(qkv + (size_t)(q0 + row) * 3072 + h * 64 + col);
    *(uint4*)(&Qs[row * LQ + col]) = v;
  }
  __syncthreads();
  bf16x8 qa[2];
#pragma unroll
  for (int kq = 0; kq < 2; ++kq)
    qa[kq] = *(const bf16x8*)(&Qs[(w * 16 + (l & 15)) * LQ + kq * 32 + (l >> 4) * 8]);

  f32x4 oacc[4] = {};
  float mi[4], li[4];
#pragma unroll
  for (int r = 0; r < 4; ++r) { mi[r] = -1e30f; li[r] = 0.f; }

  for (int kt = 0; kt < kS; kt += 128) {
    __syncthreads();  // prev iter done reading Ks/Vs
    // stage K-tile [128][64]
#pragma unroll
    for (int r = 0; r < 4; ++r) {
      int chunk = r * 256 + tid, row = chunk >> 3, col = (chunk & 7) * 8;
      uint4 v = *(const uint4*)(qkv + (size_t)(kt + row) * 3072 + kD + h * 64 + col);
      *(uint4*)(&Ks[row * LQ + col]) = v;
    }
    // stage V^T tile [64][128]
#pragma unroll
    for (int r = 0; r < 4; ++r) {
      int chunk = r * 256 + tid, row = chunk >> 4, col = (chunk & 15) * 8;
      uint4 v = *(const uint4*)(vt + (size_t)h * 64 * kS + (size_t)row * kS + kt + col);
      *(uint4*)(&Vs[row * LV + col]) = v;
    }
    __syncthreads();

    // S = Q K^T  (16 q-rows x 128 cols per wave)
    f32x4 s[8];
#pragma unroll
    for (int n = 0; n < 8; ++n) {
      f32x4 z = {};
      bf16x8 kb0 = *(const bf16x8*)(&Ks[(n * 16 + (l & 15)) * LQ + (l >> 4) * 8]);
      bf16x8 kb1 = *(const bf16x8*)(&Ks[(n * 16 + (l & 15)) * LQ + 32 + (l >> 4) * 8]);
      z = __builtin_amdgcn_mfma_f32_16x16x32_bf16(qa[0], kb0, z, 0, 0, 0);
      z = __builtin_amdgcn_mfma_f32_16x16x32_bf16(qa[1], kb1, z, 0, 0, 0);
      s[n] = z;
    }
    // online softmax (rows live on 16 lanes sharing l>>4; cols = l&15 across 8 frags)
    float alpha[4];
#pragma unroll
    for (int r = 0; r < 4; ++r) {
      float m = -1e30f;
#pragma unroll
      for (int n = 0; n < 8; ++n) m = fmaxf(m, s[n][r]);
#pragma unroll
      for (int d = 1; d < 16; d <<= 1) m = fmaxf(m, __shfl_xor(m, d));
      m *= 0.125f;  // 1/sqrt(DK); positive scale commutes with max
      float mn = fmaxf(mi[r], m);
      alpha[r] = __expf(mi[r] - mn);
      mi[r] = mn;
      li[r] *= alpha[r];
    }
#pragma unroll
    for (int n = 0; n < 4; ++n)
#pragma unroll
      for (int r = 0; r < 4; ++r) oacc[n][r] *= alpha[r];
    float rs[4] = {0.f, 0.f, 0.f, 0.f};
#pragma unroll
    for (int n = 0; n < 8; ++n)
#pragma unroll
      for (int r = 0; r < 4; ++r) {
        float pv = __expf(s[n][r] * 0.125f - mi[r]);
        rs[r] += pv;
        Ps[w][((l >> 4) * 4 + r) * LV + n * 16 + (l & 15)] = f2b(pv);
      }
#pragma unroll
    for (int r = 0; r < 4; ++r) {
      float t = rs[r];
#pragma unroll
      for (int d = 1; d < 16; d <<= 1) t += __shfl_xor(t, d);
      li[r] += t;
    }
    // O += P V   (P 16x128 from own-wave LDS region; V^T in Vs)
    bf16x8 pa[4];
#pragma unroll
    for (int ks = 0; ks < 4; ++ks)
      pa[ks] = *(const bf16x8*)(&Ps[w][(l & 15) * LV + ks * 32 + (l >> 4) * 8]);
#pragma unroll
    for (int n = 0; n < 4; ++n)
#pragma unroll
      for (int ks = 0; ks < 4; ++ks) {
        bf16x8 vb = *(const bf16x8*)(&Vs[(n * 16 + (l & 15)) * LV + ks * 32 + (l >> 4) * 8]);
        oacc[n] = __builtin_amdgcn_mfma_f32_16x16x32_bf16(pa[ks], vb, oacc[n], 0, 0, 0);
      }
  }
  // epilogue: normalize, write og[h][s][d] (contiguous == reference reshape)
#pragma unroll
  for (int r = 0; r < 4; ++r) {
    float inv = 1.f / li[r];
    int srow = q0 + w * 16 + (l >> 4) * 4 + r;
#pragma unroll
    for (int n = 0; n < 4; ++n) {
      int d = n * 16 + (l & 15);
      og[(size_t)h * kS * kDK + (size_t)srow * kDK + d] = f2b(oacc[n][r] * inv);
    }
  }
}

extern "C" void kernel_launch(void* const* d_in, const int* in_sizes, int n_in,
                              void* d_out, int out_size, void* d_ws, size_t ws_size,
                              hipStream_t stream) {
  const float* x = (const float*)d_in[0];
  const float* wq = (const float*)d_in[1];
  const float* bq = (const float*)d_in[2];
  const float* wk = (const float*)d_in[3];
  const float* bk = (const float*)d_in[4];
  const float* wv = (const float*)d_in[5];
  const float* bv = (const float*)d_in[6];
  const float* wo = (const float*)d_in[7];
  const float* bo = (const float*)d_in[8];
  const float* w1 = (const float*)d_in[9];
  const float* b1 = (const float*)d_in[10];
  const float* w2 = (const float*)d_in[11];
  const float* b2 = (const float*)d_in[12];
  const float* ln1g = (const float*)d_in[13];
  const float* ln1b = (const float*)d_in[14];
  const float* ln2g = (const float*)d_in[15];
  const float* ln2b = (const float*)d_in[16];
  float* out = (float*)d_out;

  // Workspace plan. "pool" buffers are all dead by the time the split-K
  // partials are written, so partials alias pool base.
  //   pool:  h1(4M) wqkvt(6M) qkv(12M) vt(4M) og(4M) wot(2M) h2(4M) w1t(8M)
  //   part (O-proj, 16.8MB) aliases [h1..qkv)   (dead: after QKV gemm / flash)
  //   part (FFN2, 33.6MB)  aliases [h1..wot]    (all dead at FFN2 time)
  char* p = (char*)d_ws;
  auto alloc = [&](size_t bytes) { void* q = (void*)p; p += (bytes + 255) & ~(size_t)255; return q; };
  u16* h1 = (u16*)alloc((size_t)kS * kD * 2);
  u16* wqkvt = (u16*)alloc((size_t)3 * kD * kD * 2);
  u16* qkv = (u16*)alloc((size_t)kS * 3 * kD * 2);
  u16* vt = (u16*)alloc((size_t)kH * kDK * kS * 2);
  u16* og = (u16*)alloc((size_t)kS * kD * 2);
  u16* wot = (u16*)alloc((size_t)kD * kD * 2);
  u16* h2 = (u16*)alloc((size_t)kS * kD * 2);
  u16* w1t = (u16*)alloc((size_t)kD * kMLP * 2);
  float* bqkv = (float*)alloc((size_t)3 * kD * 4);
  float* x2 = (float*)alloc((size_t)kS * kD * 4);
  u16* fbuf = (u16*)alloc((size_t)kS * kMLP * 2);
  u16* w2t = (u16*)alloc((size_t)kMLP * kD * 2);
  float* part = (float*)d_ws;  // aliases pool (see plan above)
  const size_t strideMN = (size_t)kS * kD;

  dim3 tb(32, 8);
  transpose_cvt<<<dim3(kD / 32, kD / 32), tb, 0, stream>>>(wq, wqkvt, kD, kD);
  transpose_cvt<<<dim3(kD / 32, kD / 32), tb, 0, stream>>>(wk, wqkvt + kD * kD, kD, kD);
  transpose_cvt<<<dim3(kD / 32, kD / 32), tb, 0, stream>>>(wv, wqkvt + 2 * kD * kD, kD, kD);
  transpose_cvt<<<dim3(kD / 32, kD / 32), tb, 0, stream>>>(wo, wot, kD, kD);
  transpose_cvt<<<dim3(kMLP / 32, kD / 32), tb, 0, stream>>>(w1, w1t, kD, kMLP);
  transpose_cvt<<<dim3(kD / 32, kMLP / 32), tb, 0, stream>>>(w2, w2t, kMLP, kD);
  concat_bias<<<dim3(12), dim3(256), 0, stream>>>(bq, bk, bv, bqkv);

  ln_kernel<<<dim3(kS), dim3(256), 0, stream>>>(x, ln1g, ln1b, h1);
  // fused QKV: [2048,1024] x [3072,1024]^T -> qkv bf16 [2048,3072]
  gemm_bt<0><<<dim3(3 * kD / 128, kS / 128, 1), dim3(256), 0, stream>>>(
      h1, wqkvt, bqkv, qkv, 3 * kD, kD, kD);
  vtrans<<<dim3(kS / 64, kH), dim3(256), 0, stream>>>(qkv, vt);
  flash_attn<<<dim3(kS / 64, kH), dim3(256), 0, stream>>>(qkv, vt, og);
  // O-proj split-K=2: partials = og @ wo  (fp32)
  gemm_bt<3><<<dim3(kD / 128, kS / 128, 2), dim3(256), 0, stream>>>(
      og, wot, nullptr, part, kD, kD, kD / 2);
  // x2 = x + part0 + part1 + bo
  reduce_add<2><<<dim3(kS * kD / 4 / 256), dim3(256), 0, stream>>>(
      part, bo, x, x2, kD, strideMN);
  ln_kernel<<<dim3(kS), dim3(256), 0, stream>>>(x2, ln2g, ln2b, h2);
  // FFN1 + exact GELU -> bf16 [2048,4096]
  gemm_bt<1><<<dim3(kMLP / 128, kS / 128, 1), dim3(256), 0, stream>>>(
      h2, w1t, b1, fbuf, kMLP, kD, kD);
  // FFN2 split-K=4: partials = gelu @ w2  (fp32)
  gemm_bt<3><<<dim3(kD / 128, kS / 128, 4), dim3(256), 0, stream>>>(
      fbuf, w2t, nullptr, part, kD, kMLP, kMLP / 4);
  // out = x2 + sum(parts) + b2
  reduce_add<4><<<dim3(kS * kD / 4 / 256), dim3(256), 0, stream>>>(
      part, b2, x2, out, kD, strideMN);
}